// Round 1
// baseline (357.121 us; speedup 1.0000x reference)
//
#include <hip/hip_runtime.h>
#include <hip/hip_bf16.h>
#include <cstdint>
#include <cstddef>

typedef unsigned short u16;
typedef short bf16x8 __attribute__((ext_vector_type(8)));
typedef unsigned short u16x8 __attribute__((ext_vector_type(8)));
typedef float f32x4 __attribute__((ext_vector_type(4)));

#define S_LEN 2048
#define BATCH 2
#define DM 1024
#define NHEAD 16
#define HDIM 64
#define MROWS (S_LEN * BATCH)  // 4096

__device__ __forceinline__ u16 f32_to_bf16(float f) {
  union { float f; uint32_t u; } v; v.f = f;
  uint32_t u = v.u;
  u += 0x7FFFu + ((u >> 16) & 1u);  // RNE
  return (u16)(u >> 16);
}

__device__ __forceinline__ void gload_lds16(const void* g, void* l) {
  __builtin_amdgcn_global_load_lds(
      (const __attribute__((address_space(1))) void*)g,
      (__attribute__((address_space(3))) void*)l, 16, 0, 0);
}

// ---------------- fp32 -> bf16 cast ----------------
__global__ void cast_f32_bf16(const float* __restrict__ src, u16* __restrict__ dst, int n8) {
  int i = blockIdx.x * blockDim.x + threadIdx.x;
  const int stride = gridDim.x * blockDim.x;
  for (; i < n8; i += stride) {
    const float4* s = (const float4*)(src + (size_t)i * 8);
    float4 a = s[0];
    float4 b = s[1];
    u16x8 o;
    o[0] = f32_to_bf16(a.x); o[1] = f32_to_bf16(a.y);
    o[2] = f32_to_bf16(a.z); o[3] = f32_to_bf16(a.w);
    o[4] = f32_to_bf16(b.x); o[5] = f32_to_bf16(b.y);
    o[6] = f32_to_bf16(b.z); o[7] = f32_to_bf16(b.w);
    *(u16x8*)(dst + (size_t)i * 8) = o;
  }
}

// ---------------- bf16 GEMM: C = A @ B^T + bias ----------------
// A: (M,K) row-major bf16.  Bw: (N,K) row-major bf16 (i.e. torch Linear weight).
// MODE 0: write bf16 to permuted (H, BATCH, S, HDIM) layout (QKV projections).
// MODE 1: write fp32 row-major (final output projection).
template <int MODE>
__global__ __launch_bounds__(256) void gemm_bt(
    const u16* __restrict__ A, const u16* __restrict__ Bw, const float* __restrict__ bias,
    float* __restrict__ outF, u16* __restrict__ outP, int M, int N, int K)
{
  __shared__ u16 As[128 * 32];
  __shared__ u16 Bs[128 * 32];
  const int tid = threadIdx.x;
  const int wave = tid >> 6, lane = tid & 63;
  const int l15 = lane & 15, l4 = lane >> 4;
  const int wr = wave >> 1, wc = wave & 1;
  const int rowBase = blockIdx.y * 128, colBase = blockIdx.x * 128;

  f32x4 acc[4][4];
#pragma unroll
  for (int m = 0; m < 4; ++m)
#pragma unroll
    for (int n = 0; n < 4; ++n) acc[m][n] = (f32x4){0.f, 0.f, 0.f, 0.f};

  for (int k0 = 0; k0 < K; k0 += 32) {
    // stage A,B tiles (128x32 bf16 = 8192B each) via async global->LDS, 16B/lane
#pragma unroll
    for (int c = 0; c < 2; ++c) {
      const int ldsbyte = wave * 2048 + c * 1024;      // wave-uniform base
      const int elt = (ldsbyte >> 1) + lane * 8;       // this lane's first element
      const int r = elt >> 5, cc = elt & 31;
      gload_lds16(A + (size_t)(rowBase + r) * K + k0 + cc, (char*)As + ldsbyte);
      gload_lds16(Bw + (size_t)(colBase + r) * K + k0 + cc, (char*)Bs + ldsbyte);
    }
    __syncthreads();

    bf16x8 af[4], bfr[4];
#pragma unroll
    for (int m = 0; m < 4; ++m)
      af[m] = *(const bf16x8*)&As[(wr * 64 + m * 16 + l15) * 32 + 8 * l4];
#pragma unroll
    for (int n = 0; n < 4; ++n)
      bfr[n] = *(const bf16x8*)&Bs[(wc * 64 + n * 16 + l15) * 32 + 8 * l4];
#pragma unroll
    for (int m = 0; m < 4; ++m)
#pragma unroll
      for (int n = 0; n < 4; ++n)
        acc[m][n] = __builtin_amdgcn_mfma_f32_16x16x32_bf16(af[m], bfr[n], acc[m][n], 0, 0, 0);
    __syncthreads();
  }

#pragma unroll
  for (int m = 0; m < 4; ++m)
#pragma unroll
    for (int n = 0; n < 4; ++n)
#pragma unroll
      for (int j = 0; j < 4; ++j) {
        const int row = rowBase + wr * 64 + m * 16 + 4 * l4 + j;
        const int col = colBase + wc * 64 + n * 16 + l15;
        const float vv = acc[m][n][j] + bias[col];
        if (MODE == 0) {
          // row = s*BATCH + b ; col = h*HDIM + dh  ->  [((h*BATCH+b)*S + s)*HDIM + dh]
          const int s = row >> 1, b = row & 1, h = col >> 6, dh = col & 63;
          outP[((size_t)(h * BATCH + b) * S_LEN + s) * HDIM + dh] = f32_to_bf16(vv);
        } else {
          outF[(size_t)row * N + col] = vv;
        }
      }
}

// ---------------- flash attention ----------------
// Q/K/V/O in (H, BATCH, S, HDIM) bf16. mask fp32 (S,S), additive.
__global__ __launch_bounds__(256) void flash_attn(
    const u16* __restrict__ Qh, const u16* __restrict__ Kh, const u16* __restrict__ Vh,
    const float* __restrict__ mask, u16* __restrict__ Ob)
{
  const int hb = blockIdx.y;           // h*BATCH + b
  const int qb = blockIdx.x * 64;      // q block base
  const u16* Qp = Qh + (size_t)hb * S_LEN * HDIM;
  const u16* Kp = Kh + (size_t)hb * S_LEN * HDIM;
  const u16* Vp = Vh + (size_t)hb * S_LEN * HDIM;
  u16* Op = Ob + (size_t)hb * S_LEN * HDIM;
  const int tid = threadIdx.x;
  const int wave = tid >> 6, lane = tid & 63;
  const int l15 = lane & 15, l4 = lane >> 4;
  const int qrow0 = qb + wave * 16;    // each wave owns 16 q rows

  // Q A-fragments (row = l15, k = dh), hoisted for the whole kernel
  bf16x8 aq[2];
  aq[0] = *(const bf16x8*)&Qp[(size_t)(qrow0 + l15) * HDIM + 8 * l4];
  aq[1] = *(const bf16x8*)&Qp[(size_t)(qrow0 + l15) * HDIM + 32 + 8 * l4];

  float m_run[4] = {-1e30f, -1e30f, -1e30f, -1e30f};
  float l_run[4] = {0.f, 0.f, 0.f, 0.f};
  f32x4 oacc[4];
#pragma unroll
  for (int n = 0; n < 4; ++n) oacc[n] = (f32x4){0.f, 0.f, 0.f, 0.f};

  __shared__ u16 Vt[64][32];        // V tile transposed: [dh][key]
  __shared__ u16 Plds[4][16][32];   // per-wave P tile: [q][key]
  const float sc = 0.125f;          // 1/sqrt(64)

  for (int kt = 0; kt < S_LEN; kt += 32) {
    __syncthreads();  // protect Vt from previous iteration's readers
    {
      // cooperative transpose-stage of V tile (32 keys x 64 dh)
      const int r = tid >> 3, c8 = (tid & 7) * 8;
      bf16x8 vv = *(const bf16x8*)&Vp[(size_t)(kt + r) * HDIM + c8];
#pragma unroll
      for (int e = 0; e < 8; ++e) Vt[c8 + e][r] = (u16)vv[e];
    }
    __syncthreads();

    // QK^T: two 16-key halves, K accumulated over dh (2 MFMAs each)
    f32x4 cfr[2];
#pragma unroll
    for (int half = 0; half < 2; ++half) {
      bf16x8 kb0 = *(const bf16x8*)&Kp[(size_t)(kt + half * 16 + l15) * HDIM + 8 * l4];
      bf16x8 kb1 = *(const bf16x8*)&Kp[(size_t)(kt + half * 16 + l15) * HDIM + 32 + 8 * l4];
      f32x4 z = (f32x4){0.f, 0.f, 0.f, 0.f};
      z = __builtin_amdgcn_mfma_f32_16x16x32_bf16(aq[0], kb0, z, 0, 0, 0);
      z = __builtin_amdgcn_mfma_f32_16x16x32_bf16(aq[1], kb1, z, 0, 0, 0);
      cfr[half] = z;
    }

    // scale + additive mask; rows r_j = 4*l4 + j, col = l15 (+16)
    float p0[4], p1[4], tm[4];
#pragma unroll
    for (int j = 0; j < 4; ++j) {
      const size_t mrow = (size_t)(qrow0 + 4 * l4 + j) * S_LEN + kt;
      float s0 = cfr[0][j] * sc + mask[mrow + l15];
      float s1 = cfr[1][j] * sc + mask[mrow + 16 + l15];
      p0[j] = s0; p1[j] = s1;
      tm[j] = fmaxf(s0, s1);
    }
    // row max across the 16-lane group
#pragma unroll
    for (int off = 1; off <= 8; off <<= 1)
#pragma unroll
      for (int j = 0; j < 4; ++j) tm[j] = fmaxf(tm[j], __shfl_xor(tm[j], off));

    float fac[4], rs[4];
#pragma unroll
    for (int j = 0; j < 4; ++j) {
      const float mn = fmaxf(m_run[j], tm[j]);
      fac[j] = __expf(m_run[j] - mn);
      p0[j] = __expf(p0[j] - mn);
      p1[j] = __expf(p1[j] - mn);
      m_run[j] = mn;
      rs[j] = p0[j] + p1[j];
    }
#pragma unroll
    for (int off = 1; off <= 8; off <<= 1)
#pragma unroll
      for (int j = 0; j < 4; ++j) rs[j] += __shfl_xor(rs[j], off);
#pragma unroll
    for (int j = 0; j < 4; ++j) l_run[j] = l_run[j] * fac[j] + rs[j];
#pragma unroll
    for (int n = 0; n < 4; ++n)
#pragma unroll
      for (int j = 0; j < 4; ++j) oacc[n][j] *= fac[j];

    // P (D-layout) -> LDS -> A-layout fragment (wave-local, lockstep-safe)
#pragma unroll
    for (int j = 0; j < 4; ++j) {
      Plds[wave][4 * l4 + j][l15] = f32_to_bf16(p0[j]);
      Plds[wave][4 * l4 + j][16 + l15] = f32_to_bf16(p1[j]);
    }
    __builtin_amdgcn_sched_barrier(0);
    bf16x8 pa = *(const bf16x8*)&Plds[wave][l15][8 * l4];

    // PV: O[q][dh] += P[q][key] * V[key][dh]
#pragma unroll
    for (int n = 0; n < 4; ++n) {
      bf16x8 vb = *(const bf16x8*)&Vt[n * 16 + l15][8 * l4];
      oacc[n] = __builtin_amdgcn_mfma_f32_16x16x32_bf16(pa, vb, oacc[n], 0, 0, 0);
    }
  }

#pragma unroll
  for (int n = 0; n < 4; ++n)
#pragma unroll
    for (int j = 0; j < 4; ++j) {
      const float ov = oacc[n][j] / l_run[j];
      Op[(size_t)(qrow0 + 4 * l4 + j) * HDIM + n * 16 + l15] = f32_to_bf16(ov);
    }
}

// ---------------- launch ----------------
extern "C" void kernel_launch(void* const* d_in, const int* in_sizes, int n_in,
                              void* d_out, int out_size, void* d_ws, size_t ws_size,
                              hipStream_t stream) {
  const float* q    = (const float*)d_in[0];
  const float* k    = (const float*)d_in[1];
  const float* v    = (const float*)d_in[2];
  const float* mask = (const float*)d_in[3];
  const float* Wq   = (const float*)d_in[4];
  const float* bq   = (const float*)d_in[5];
  const float* Wk   = (const float*)d_in[6];
  const float* bk   = (const float*)d_in[7];
  const float* Wv   = (const float*)d_in[8];
  const float* bv   = (const float*)d_in[9];
  const float* Wo   = (const float*)d_in[10];
  const float* bo   = (const float*)d_in[11];
  float* out = (float*)d_out;

  char* ws = (char*)d_ws;
  const size_t TEN = (size_t)MROWS * DM * sizeof(u16);  // 8 MB
  const size_t WSZ = (size_t)DM * DM * sizeof(u16);     // 2 MB
  u16* qb_ = (u16*)(ws);
  u16* kb_ = (u16*)(ws + TEN);
  u16* vb_ = (u16*)(ws + 2 * TEN);
  u16* wqb = (u16*)(ws + 3 * TEN);
  u16* wkb = (u16*)(ws + 3 * TEN + WSZ);
  u16* wvb = (u16*)(ws + 3 * TEN + 2 * WSZ);
  u16* wob = (u16*)(ws + 3 * TEN + 3 * WSZ);
  u16* Qh  = (u16*)(ws + 3 * TEN + 4 * WSZ);
  u16* Kh  = (u16*)(ws + 4 * TEN + 4 * WSZ);
  u16* Vh  = (u16*)(ws + 5 * TEN + 4 * WSZ);
  u16* Ob  = (u16*)(ws + 6 * TEN + 4 * WSZ);
  // total ws use: 64 MB

  const int n8_t = MROWS * DM / 8;  // 524288
  const int n8_w = DM * DM / 8;     // 131072
  cast_f32_bf16<<<2048, 256, 0, stream>>>(q, qb_, n8_t);
  cast_f32_bf16<<<2048, 256, 0, stream>>>(k, kb_, n8_t);
  cast_f32_bf16<<<2048, 256, 0, stream>>>(v, vb_, n8_t);
  cast_f32_bf16<<<512, 256, 0, stream>>>(Wq, wqb, n8_w);
  cast_f32_bf16<<<512, 256, 0, stream>>>(Wk, wkb, n8_w);
  cast_f32_bf16<<<512, 256, 0, stream>>>(Wv, wvb, n8_w);
  cast_f32_bf16<<<512, 256, 0, stream>>>(Wo, wob, n8_w);

  const dim3 ggrid(DM / 128, MROWS / 128);  // (8, 32)
  gemm_bt<0><<<ggrid, 256, 0, stream>>>(qb_, wqb, bq, nullptr, Qh, MROWS, DM, DM);
  gemm_bt<0><<<ggrid, 256, 0, stream>>>(kb_, wkb, bk, nullptr, Kh, MROWS, DM, DM);
  gemm_bt<0><<<ggrid, 256, 0, stream>>>(vb_, wvb, bv, nullptr, Vh, MROWS, DM, DM);

  flash_attn<<<dim3(S_LEN / 64, NHEAD * BATCH), 256, 0, stream>>>(Qh, Kh, Vh, mask, Ob);

  gemm_bt<1><<<ggrid, 256, 0, stream>>>(Ob, wob, bo, out, nullptr, MROWS, DM, DM);
}

// Round 2
// 330.820 us; speedup vs baseline: 1.0795x; 1.0795x over previous
//
#include <hip/hip_runtime.h>
#include <hip/hip_bf16.h>
#include <cstdint>
#include <cstddef>

typedef unsigned short u16;
typedef short bf16x8 __attribute__((ext_vector_type(8)));
typedef short bf16x4 __attribute__((ext_vector_type(4)));
typedef unsigned short u16x8 __attribute__((ext_vector_type(8)));
typedef unsigned short u16x4 __attribute__((ext_vector_type(4)));
typedef float f32x4 __attribute__((ext_vector_type(4)));

#define S_LEN 2048
#define BATCH 2
#define DM 1024
#define NHEAD 16
#define HDIM 64
#define MROWS (S_LEN * BATCH)  // 4096

__device__ __forceinline__ u16 f32_to_bf16(float f) {
  union { float f; uint32_t u; } v; v.f = f;
  uint32_t u = v.u;
  u += 0x7FFFu + ((u >> 16) & 1u);  // RNE
  return (u16)(u >> 16);
}

__device__ __forceinline__ void gload_lds16(const void* g, void* l) {
  __builtin_amdgcn_global_load_lds(
      (const __attribute__((address_space(1))) void*)g,
      (__attribute__((address_space(3))) void*)l, 16, 0, 0);
}

// hardware transpose read: 4 bf16 per lane from a [4][16] subtile walk
__device__ __forceinline__ bf16x4 tr_read(const void* lp) {
  bf16x4 d;
  auto p = (const __attribute__((address_space(3))) short*)lp;
  asm volatile("ds_read_b64_tr_b16 %0, %1" : "=v"(d) : "v"(p));
  return d;
}

#if __has_builtin(__builtin_amdgcn_mfma_f32_16x16x16_bf16)
#define MFMA16(a, b, c) __builtin_amdgcn_mfma_f32_16x16x16_bf16(a, b, c, 0, 0, 0)
#elif __has_builtin(__builtin_amdgcn_mfma_f32_16x16x16bf16_1k)
#define MFMA16(a, b, c) __builtin_amdgcn_mfma_f32_16x16x16bf16_1k(a, b, c, 0, 0, 0)
#else
__device__ __forceinline__ f32x4 mfma16_asm(bf16x4 a, bf16x4 b, f32x4 c) {
  f32x4 d;
  asm volatile("v_mfma_f32_16x16x16_bf16 %0, %1, %2, %3\n\ts_nop 7\n\ts_nop 7"
               : "=&v"(d) : "v"(a), "v"(b), "v"(c));
  return d;
}
#define MFMA16(a, b, c) mfma16_asm(a, b, c)
#endif

// ---------------- fp32 -> bf16 cast ----------------
__global__ void cast_f32_bf16(const float* __restrict__ src, u16* __restrict__ dst, int n8) {
  int i = blockIdx.x * blockDim.x + threadIdx.x;
  const int stride = gridDim.x * blockDim.x;
  for (; i < n8; i += stride) {
    const float4* s = (const float4*)(src + (size_t)i * 8);
    float4 a = s[0];
    float4 b = s[1];
    u16x8 o;
    o[0] = f32_to_bf16(a.x); o[1] = f32_to_bf16(a.y);
    o[2] = f32_to_bf16(a.z); o[3] = f32_to_bf16(a.w);
    o[4] = f32_to_bf16(b.x); o[5] = f32_to_bf16(b.y);
    o[6] = f32_to_bf16(b.z); o[7] = f32_to_bf16(b.w);
    *(u16x8*)(dst + (size_t)i * 8) = o;
  }
}

// ---------------- bf16 GEMM: C = A @ B^T + bias ----------------
template <int MODE>
__global__ __launch_bounds__(256) void gemm_bt(
    const u16* __restrict__ A, const u16* __restrict__ Bw, const float* __restrict__ bias,
    float* __restrict__ outF, u16* __restrict__ outP, int M, int N, int K)
{
  __shared__ u16 As[128 * 32];
  __shared__ u16 Bs[128 * 32];
  const int tid = threadIdx.x;
  const int wave = tid >> 6, lane = tid & 63;
  const int l15 = lane & 15, l4 = lane >> 4;
  const int wr = wave >> 1, wc = wave & 1;
  const int rowBase = blockIdx.y * 128, colBase = blockIdx.x * 128;

  f32x4 acc[4][4];
#pragma unroll
  for (int m = 0; m < 4; ++m)
#pragma unroll
    for (int n = 0; n < 4; ++n) acc[m][n] = (f32x4){0.f, 0.f, 0.f, 0.f};

  for (int k0 = 0; k0 < K; k0 += 32) {
#pragma unroll
    for (int c = 0; c < 2; ++c) {
      const int ldsbyte = wave * 2048 + c * 1024;
      const int elt = (ldsbyte >> 1) + lane * 8;
      const int r = elt >> 5, cc = elt & 31;
      gload_lds16(A + (size_t)(rowBase + r) * K + k0 + cc, (char*)As + ldsbyte);
      gload_lds16(Bw + (size_t)(colBase + r) * K + k0 + cc, (char*)Bs + ldsbyte);
    }
    __syncthreads();

    bf16x8 af[4], bfr[4];
#pragma unroll
    for (int m = 0; m < 4; ++m)
      af[m] = *(const bf16x8*)&As[(wr * 64 + m * 16 + l15) * 32 + 8 * l4];
#pragma unroll
    for (int n = 0; n < 4; ++n)
      bfr[n] = *(const bf16x8*)&Bs[(wc * 64 + n * 16 + l15) * 32 + 8 * l4];
#pragma unroll
    for (int m = 0; m < 4; ++m)
#pragma unroll
      for (int n = 0; n < 4; ++n)
        acc[m][n] = __builtin_amdgcn_mfma_f32_16x16x32_bf16(af[m], bfr[n], acc[m][n], 0, 0, 0);
    __syncthreads();
  }

#pragma unroll
  for (int m = 0; m < 4; ++m)
#pragma unroll
    for (int n = 0; n < 4; ++n)
#pragma unroll
      for (int j = 0; j < 4; ++j) {
        const int row = rowBase + wr * 64 + m * 16 + 4 * l4 + j;
        const int col = colBase + wc * 64 + n * 16 + l15;
        const float vv = acc[m][n][j] + bias[col];
        if (MODE == 0) {
          const int s = row >> 1, b = row & 1, h = col >> 6, dh = col & 63;
          outP[((size_t)(h * BATCH + b) * S_LEN + s) * HDIM + dh] = f32_to_bf16(vv);
        } else {
          outF[(size_t)row * N + col] = vv;
        }
      }
}

// ---------------- flash attention v2 (swapped QK^T, tr-read PV) ----------------
// V staged into LDS with subtiled layout [dh/16][key/4][key%4][dh%16] so that
// ds_read_b64_tr_b16 at per-lane addr base+8*lane yields the 16x16x16 A-frag
// of V^T (row = dh = lane&15, k = key = 4*(lane>>4)+e).
__device__ __forceinline__ void stageV(const u16* __restrict__ Vp, int kt, u16* dst, int tid) {
#pragma unroll
  for (int h = 0; h < 2; ++h) {
    const int c = tid + 256 * h;                     // chunk id, 16B each
    const int key = 4 * ((c >> 3) & 15) + ((c >> 1) & 3);
    const int dh  = 16 * (c >> 7) + 8 * (c & 1);
    gload_lds16(Vp + (size_t)(kt + key) * HDIM + dh, (char*)dst + 16 * c);
  }
}

__global__ __launch_bounds__(256) void flash_attn(
    const u16* __restrict__ Qh, const u16* __restrict__ Kh, const u16* __restrict__ Vh,
    const float* __restrict__ mask, u16* __restrict__ Ob)
{
  const int hb = blockIdx.y;
  const int qb = blockIdx.x * 64;
  const u16* Qp = Qh + (size_t)hb * S_LEN * HDIM;
  const u16* Kp = Kh + (size_t)hb * S_LEN * HDIM;
  const u16* Vp = Vh + (size_t)hb * S_LEN * HDIM;
  u16* Op = Ob + (size_t)hb * S_LEN * HDIM;
  const int tid = threadIdx.x;
  const int wave = tid >> 6, lane = tid & 63;
  const int l15 = lane & 15, l4 = lane >> 4;
  const int qrow = qb + wave * 16 + l15;   // this lane's q row

  // Q B-frags (col = q = l15, k = dh), hoisted
  bf16x8 bq0 = *(const bf16x8*)&Qp[(size_t)qrow * HDIM + 8 * l4];
  bf16x8 bq1 = *(const bf16x8*)&Qp[(size_t)qrow * HDIM + 32 + 8 * l4];

  __shared__ u16 Vlds[2][4096];   // two 64key x 64dh subtiled buffers (8KB each)
  stageV(Vp, 0, &Vlds[0][0], tid);

  float m_run = -1e30f, l_run = 0.f;
  f32x4 oacc[4];
#pragma unroll
  for (int D = 0; D < 4; ++D) oacc[D] = (f32x4){0.f, 0.f, 0.f, 0.f};
  const float sc = 0.125f;  // 1/sqrt(64)
  int cur = 0;

  for (int kt = 0; kt < S_LEN; kt += 64) {
    // ---- QK^T swapped: S^T[key][q] = mfma(K-frag, Q-frag) ----
    f32x4 st[4];
#pragma unroll
    for (int kb = 0; kb < 4; ++kb) {
      bf16x8 ka0 = *(const bf16x8*)&Kp[(size_t)(kt + 16 * kb + l15) * HDIM + 8 * l4];
      bf16x8 ka1 = *(const bf16x8*)&Kp[(size_t)(kt + 16 * kb + l15) * HDIM + 32 + 8 * l4];
      f32x4 z = (f32x4){0.f, 0.f, 0.f, 0.f};
      z = __builtin_amdgcn_mfma_f32_16x16x32_bf16(ka0, bq0, z, 0, 0, 0);
      z = __builtin_amdgcn_mfma_f32_16x16x32_bf16(ka1, bq1, z, 0, 0, 0);
      st[kb] = z;
    }

    // ---- mask + online softmax (lane owns one q row; 16 key-values) ----
    float p[16];
#pragma unroll
    for (int kb = 0; kb < 4; ++kb) {
      const float4 mk = *(const float4*)&mask[(size_t)qrow * S_LEN + kt + 16 * kb + 4 * l4];
      p[4 * kb + 0] = st[kb][0] * sc + mk.x;
      p[4 * kb + 1] = st[kb][1] * sc + mk.y;
      p[4 * kb + 2] = st[kb][2] * sc + mk.z;
      p[4 * kb + 3] = st[kb][3] * sc + mk.w;
    }
    float tm = p[0];
#pragma unroll
    for (int i = 1; i < 16; ++i) tm = fmaxf(tm, p[i]);
    tm = fmaxf(tm, __shfl_xor(tm, 16));
    tm = fmaxf(tm, __shfl_xor(tm, 32));

    if (!__all(tm - m_run <= 8.0f)) {           // defer-max (T13)
      const float mn = fmaxf(m_run, tm);
      const float fac = __expf(m_run - mn);
#pragma unroll
      for (int D = 0; D < 4; ++D)
#pragma unroll
        for (int j = 0; j < 4; ++j) oacc[D][j] *= fac;
      l_run *= fac;
      m_run = mn;
    }

    float rs = 0.f;
    bf16x4 pb[4];
#pragma unroll
    for (int kb = 0; kb < 4; ++kb)
#pragma unroll
      for (int e = 0; e < 4; ++e) {
        const float pe = __expf(p[4 * kb + e] - m_run);
        rs += pe;
        pb[kb][e] = (short)f32_to_bf16(pe);
      }
    rs += __shfl_xor(rs, 16);
    rs += __shfl_xor(rs, 32);
    l_run += rs;

    __syncthreads();   // V buf[cur] staged & visible; everyone done with buf[cur^1]

    // ---- PV: O^T[dh][q] += V^T-frag x P^T-frag ----
    const char* vb = (const char*)&Vlds[cur][0] + 8 * lane;
    bf16x4 va[4][4];
#pragma unroll
    for (int D = 0; D < 4; ++D)
#pragma unroll
      for (int kb = 0; kb < 4; ++kb)
        va[D][kb] = tr_read(vb + 2048 * D + 512 * kb);
    asm volatile("s_waitcnt lgkmcnt(0)" ::: "memory");
    __builtin_amdgcn_sched_barrier(0);
#pragma unroll
    for (int D = 0; D < 4; ++D)
#pragma unroll
      for (int kb = 0; kb < 4; ++kb)
        oacc[D] = MFMA16(va[D][kb], pb[kb], oacc[D]);

    // prefetch next V tile into the other buffer (consumed after next barrier)
    if (kt + 64 < S_LEN) stageV(Vp, kt + 64, &Vlds[cur ^ 1][0], tid);
    cur ^= 1;
  }

  // ---- epilogue: O[q][dh] = O^T / l ----
  const float inv = 1.0f / l_run;
#pragma unroll
  for (int D = 0; D < 4; ++D) {
    u16x4 ov;
#pragma unroll
    for (int j = 0; j < 4; ++j) ov[j] = f32_to_bf16(oacc[D][j] * inv);
    *(u16x4*)&Op[(size_t)qrow * HDIM + 16 * D + 4 * l4] = ov;
  }
}

// ---------------- launch ----------------
extern "C" void kernel_launch(void* const* d_in, const int* in_sizes, int n_in,
                              void* d_out, int out_size, void* d_ws, size_t ws_size,
                              hipStream_t stream) {
  const float* q    = (const float*)d_in[0];
  const float* k    = (const float*)d_in[1];
  const float* v    = (const float*)d_in[2];
  const float* mask = (const float*)d_in[3];
  const float* Wq   = (const float*)d_in[4];
  const float* bq   = (const float*)d_in[5];
  const float* Wk   = (const float*)d_in[6];
  const float* bk   = (const float*)d_in[7];
  const float* Wv   = (const float*)d_in[8];
  const float* bv   = (const float*)d_in[9];
  const float* Wo   = (const float*)d_in[10];
  const float* bo   = (const float*)d_in[11];
  float* out = (float*)d_out;

  char* ws = (char*)d_ws;
  const size_t TEN = (size_t)MROWS * DM * sizeof(u16);  // 8 MB
  const size_t WSZ = (size_t)DM * DM * sizeof(u16);     // 2 MB
  u16* qb_ = (u16*)(ws);
  u16* kb_ = (u16*)(ws + TEN);
  u16* vb_ = (u16*)(ws + 2 * TEN);
  u16* wqb = (u16*)(ws + 3 * TEN);
  u16* wkb = (u16*)(ws + 3 * TEN + WSZ);
  u16* wvb = (u16*)(ws + 3 * TEN + 2 * WSZ);
  u16* wob = (u16*)(ws + 3 * TEN + 3 * WSZ);
  u16* Qh  = (u16*)(ws + 3 * TEN + 4 * WSZ);
  u16* Kh  = (u16*)(ws + 4 * TEN + 4 * WSZ);
  u16* Vh  = (u16*)(ws + 5 * TEN + 4 * WSZ);
  u16* Ob  = (u16*)(ws + 6 * TEN + 4 * WSZ);

  const int n8_t = MROWS * DM / 8;
  const int n8_w = DM * DM / 8;
  cast_f32_bf16<<<2048, 256, 0, stream>>>(q, qb_, n8_t);
  cast_f32_bf16<<<2048, 256, 0, stream>>>(k, kb_, n8_t);
  cast_f32_bf16<<<2048, 256, 0, stream>>>(v, vb_, n8_t);
  cast_f32_bf16<<<512, 256, 0, stream>>>(Wq, wqb, n8_w);
  cast_f32_bf16<<<512, 256, 0, stream>>>(Wk, wkb, n8_w);
  cast_f32_bf16<<<512, 256, 0, stream>>>(Wv, wvb, n8_w);
  cast_f32_bf16<<<512, 256, 0, stream>>>(Wo, wob, n8_w);

  const dim3 ggrid(DM / 128, MROWS / 128);
  gemm_bt<0><<<ggrid, 256, 0, stream>>>(qb_, wqb, bq, nullptr, Qh, MROWS, DM, DM);
  gemm_bt<0><<<ggrid, 256, 0, stream>>>(kb_, wkb, bk, nullptr, Kh, MROWS, DM, DM);
  gemm_bt<0><<<ggrid, 256, 0, stream>>>(vb_, wvb, bv, nullptr, Vh, MROWS, DM, DM);

  flash_attn<<<dim3(S_LEN / 64, NHEAD * BATCH), 256, 0, stream>>>(Qh, Kh, Vh, mask, Ob);

  gemm_bt<1><<<ggrid, 256, 0, stream>>>(Ob, wob, bo, out, nullptr, MROWS, DM, DM);
}

// Round 3
// 311.151 us; speedup vs baseline: 1.1477x; 1.0632x over previous
//
#include <hip/hip_runtime.h>
#include <hip/hip_bf16.h>
#include <cstdint>
#include <cstddef>

typedef unsigned short u16;
typedef short bf16x8 __attribute__((ext_vector_type(8)));
typedef short bf16x4 __attribute__((ext_vector_type(4)));
typedef unsigned short u16x8 __attribute__((ext_vector_type(8)));
typedef unsigned short u16x4 __attribute__((ext_vector_type(4)));
typedef float f32x4 __attribute__((ext_vector_type(4)));

#define S_LEN 2048
#define BATCH 2
#define DM 1024
#define NHEAD 16
#define HDIM 64
#define MROWS (S_LEN * BATCH)  // 4096

__device__ __forceinline__ u16 f32_to_bf16(float f) {
  union { float f; uint32_t u; } v; v.f = f;
  uint32_t u = v.u;
  u += 0x7FFFu + ((u >> 16) & 1u);  // RNE
  return (u16)(u >> 16);
}

__device__ __forceinline__ void gload_lds16(const void* g, void* l) {
  __builtin_amdgcn_global_load_lds(
      (const __attribute__((address_space(1))) void*)g,
      (__attribute__((address_space(3))) void*)l, 16, 0, 0);
}

// hardware transpose read: 4 bf16 per lane from a [4][16] subtile walk
__device__ __forceinline__ bf16x4 tr_read(const void* lp) {
  bf16x4 d;
  auto p = (const __attribute__((address_space(3))) short*)lp;
  asm volatile("ds_read_b64_tr_b16 %0, %1" : "=v"(d) : "v"(p));
  return d;
}

#if __has_builtin(__builtin_amdgcn_mfma_f32_16x16x16_bf16)
#define MFMA16(a, b, c) __builtin_amdgcn_mfma_f32_16x16x16_bf16(a, b, c, 0, 0, 0)
#elif __has_builtin(__builtin_amdgcn_mfma_f32_16x16x16bf16_1k)
#define MFMA16(a, b, c) __builtin_amdgcn_mfma_f32_16x16x16bf16_1k(a, b, c, 0, 0, 0)
#else
__device__ __forceinline__ f32x4 mfma16_asm(bf16x4 a, bf16x4 b, f32x4 c) {
  f32x4 d;
  asm volatile("v_mfma_f32_16x16x16_bf16 %0, %1, %2, %3\n\ts_nop 7\n\ts_nop 7"
               : "=&v"(d) : "v"(a), "v"(b), "v"(c));
  return d;
}
#define MFMA16(a, b, c) mfma16_asm(a, b, c)
#endif

// ---------------- fused fp32 -> bf16 casts (4 tensors / launch) ----------------
__global__ void cast4_f32_bf16(const float* __restrict__ s0, u16* __restrict__ d0,
                               const float* __restrict__ s1, u16* __restrict__ d1,
                               const float* __restrict__ s2, u16* __restrict__ d2,
                               const float* __restrict__ s3, u16* __restrict__ d3,
                               int n8) {
  const int which = blockIdx.y;
  const float* src = which == 0 ? s0 : which == 1 ? s1 : which == 2 ? s2 : s3;
  u16* dst = which == 0 ? d0 : which == 1 ? d1 : which == 2 ? d2 : d3;
  int i = blockIdx.x * blockDim.x + threadIdx.x;
  const int stride = gridDim.x * blockDim.x;
  for (; i < n8; i += stride) {
    const float4* s = (const float4*)(src + (size_t)i * 8);
    float4 a = s[0];
    float4 b = s[1];
    u16x8 o;
    o[0] = f32_to_bf16(a.x); o[1] = f32_to_bf16(a.y);
    o[2] = f32_to_bf16(a.z); o[3] = f32_to_bf16(a.w);
    o[4] = f32_to_bf16(b.x); o[5] = f32_to_bf16(b.y);
    o[6] = f32_to_bf16(b.z); o[7] = f32_to_bf16(b.w);
    *(u16x8*)(dst + (size_t)i * 8) = o;
  }
}

// ---------------- bf16 GEMM: C = A @ B^T + bias  (BM=128, BN=64, BK=32) --------
// grid = (N/64, M/128), 2 blocks/CU so barrier stalls overlap across blocks.
template <int MODE>
__global__ __launch_bounds__(256) void gemm_bt(
    const u16* __restrict__ A, const u16* __restrict__ Bw, const float* __restrict__ bias,
    float* __restrict__ outF, u16* __restrict__ outP, int M, int N, int K)
{
  __shared__ u16 As[128 * 32];
  __shared__ u16 Bs[64 * 32];
  const int tid = threadIdx.x;
  const int wave = tid >> 6, lane = tid & 63;
  const int l15 = lane & 15, l4 = lane >> 4;
  const int wr = wave >> 1, wc = wave & 1;
  const int rowBase = blockIdx.y * 128, colBase = blockIdx.x * 64;

  f32x4 acc[4][2];
#pragma unroll
  for (int m = 0; m < 4; ++m)
#pragma unroll
    for (int n = 0; n < 2; ++n) acc[m][n] = (f32x4){0.f, 0.f, 0.f, 0.f};

  for (int k0 = 0; k0 < K; k0 += 32) {
#pragma unroll
    for (int c = 0; c < 2; ++c) {
      const int ldsbyte = wave * 2048 + c * 1024;
      const int elt = (ldsbyte >> 1) + lane * 8;
      const int r = elt >> 5, cc = elt & 31;
      gload_lds16(A + (size_t)(rowBase + r) * K + k0 + cc, (char*)As + ldsbyte);
    }
    {
      const int ldsbyte = wave * 1024;
      const int elt = (ldsbyte >> 1) + lane * 8;
      const int r = elt >> 5, cc = elt & 31;
      gload_lds16(Bw + (size_t)(colBase + r) * K + k0 + cc, (char*)Bs + ldsbyte);
    }
    __syncthreads();

    bf16x8 af[4], bfr[2];
#pragma unroll
    for (int m = 0; m < 4; ++m)
      af[m] = *(const bf16x8*)&As[(wr * 64 + m * 16 + l15) * 32 + 8 * l4];
#pragma unroll
    for (int n = 0; n < 2; ++n)
      bfr[n] = *(const bf16x8*)&Bs[(wc * 32 + n * 16 + l15) * 32 + 8 * l4];
#pragma unroll
    for (int m = 0; m < 4; ++m)
#pragma unroll
      for (int n = 0; n < 2; ++n)
        acc[m][n] = __builtin_amdgcn_mfma_f32_16x16x32_bf16(af[m], bfr[n], acc[m][n], 0, 0, 0);
    __syncthreads();
  }

#pragma unroll
  for (int m = 0; m < 4; ++m)
#pragma unroll
    for (int n = 0; n < 2; ++n)
#pragma unroll
      for (int j = 0; j < 4; ++j) {
        const int row = rowBase + wr * 64 + m * 16 + 4 * l4 + j;
        const int col = colBase + wc * 32 + n * 16 + l15;
        const float vv = acc[m][n][j] + bias[col];
        if (MODE == 0) {
          const int s = row >> 1, b = row & 1, h = col >> 6, dh = col & 63;
          outP[((size_t)(h * BATCH + b) * S_LEN + s) * HDIM + dh] = f32_to_bf16(vv);
        } else {
          outF[(size_t)row * N + col] = vv;
        }
      }
}

// ---------------- flash attention v3 (pipelined) ----------------
// V LDS layout [dh/16][key/4][key%4][dh%16]: tr_read at base+8*lane yields the
// 16x16x16 A-frag of V^T (row = dh = lane&15, k = key = 4*(lane>>4)+e).
__device__ __forceinline__ void stageV(const u16* __restrict__ Vp, int kt, u16* dst, int tid) {
#pragma unroll
  for (int h = 0; h < 2; ++h) {
    const int c = tid + 256 * h;                     // chunk id, 16B each
    const int key = 4 * ((c >> 3) & 15) + ((c >> 1) & 3);
    const int dh  = 16 * (c >> 7) + 8 * (c & 1);
    gload_lds16(Vp + (size_t)(kt + key) * HDIM + dh, (char*)dst + 16 * c);
  }
}

// One 64-key tile: consume (kc,mc), prefetch (kn,mn) for tile kt+64,
// counted-vmcnt + raw barrier, stage V(t+1), PV from vbuf.
__device__ __forceinline__ void fa_step(
    int kt, bool has_next,
    const u16* __restrict__ Kp, const float* __restrict__ mask, const u16* __restrict__ Vp,
    int qrow, int l15, int l4, int lane, int tid,
    const bf16x8& bq0, const bf16x8& bq1,
    bf16x8 (&kc0)[4], bf16x8 (&kc1)[4], float4 (&mc)[4],
    bf16x8 (&kn0)[4], bf16x8 (&kn1)[4], float4 (&mn)[4],
    const u16* vbuf, u16* vnext,
    float& m_run, float& l_run, f32x4 (&oacc)[4])
{
  const float sc = 0.125f;  // 1/sqrt(64)

  // .a issue next-tile K-frag + mask loads (12 x dwordx4, stay in flight past barrier)
  if (has_next) {
    const int ktn = kt + 64;
#pragma unroll
    for (int kb = 0; kb < 4; ++kb) {
      kn0[kb] = *(const bf16x8*)&Kp[(size_t)(ktn + 16 * kb + l15) * HDIM + 8 * l4];
      kn1[kb] = *(const bf16x8*)&Kp[(size_t)(ktn + 16 * kb + l15) * HDIM + 32 + 8 * l4];
      mn[kb]  = *(const float4*)&mask[(size_t)qrow * S_LEN + ktn + 16 * kb + 4 * l4];
    }
  }

  // .b QK^T swapped: S^T[key][q] = mfma(K-frag, Q-frag)
  f32x4 st[4];
  __builtin_amdgcn_s_setprio(1);
#pragma unroll
  for (int kb = 0; kb < 4; ++kb) {
    f32x4 z = (f32x4){0.f, 0.f, 0.f, 0.f};
    z = __builtin_amdgcn_mfma_f32_16x16x32_bf16(kc0[kb], bq0, z, 0, 0, 0);
    z = __builtin_amdgcn_mfma_f32_16x16x32_bf16(kc1[kb], bq1, z, 0, 0, 0);
    st[kb] = z;
  }
  __builtin_amdgcn_s_setprio(0);

  // .c online softmax (lane owns one q row; 16 of 64 key-values)
  float p[16];
#pragma unroll
  for (int kb = 0; kb < 4; ++kb) {
    p[4 * kb + 0] = st[kb][0] * sc + mc[kb].x;
    p[4 * kb + 1] = st[kb][1] * sc + mc[kb].y;
    p[4 * kb + 2] = st[kb][2] * sc + mc[kb].z;
    p[4 * kb + 3] = st[kb][3] * sc + mc[kb].w;
  }
  float t0 = fmaxf(fmaxf(p[0], p[1]), fmaxf(p[2], p[3]));
  float t1 = fmaxf(fmaxf(p[4], p[5]), fmaxf(p[6], p[7]));
  float t2 = fmaxf(fmaxf(p[8], p[9]), fmaxf(p[10], p[11]));
  float t3 = fmaxf(fmaxf(p[12], p[13]), fmaxf(p[14], p[15]));
  float tm = fmaxf(fmaxf(t0, t1), fmaxf(t2, t3));
  tm = fmaxf(tm, __shfl_xor(tm, 16));
  tm = fmaxf(tm, __shfl_xor(tm, 32));

  if (!__all(tm - m_run <= 8.0f)) {           // defer-max (T13)
    const float mn_ = fmaxf(m_run, tm);
    const float fac = __expf(m_run - mn_);
#pragma unroll
    for (int D = 0; D < 4; ++D)
#pragma unroll
      for (int j = 0; j < 4; ++j) oacc[D][j] *= fac;
    l_run *= fac;
    m_run = mn_;
  }

  float rs = 0.f;
  bf16x4 pb[4];
#pragma unroll
  for (int kb = 0; kb < 4; ++kb)
#pragma unroll
    for (int e = 0; e < 4; ++e) {
      const float pe = __expf(p[4 * kb + e] - m_run);
      rs += pe;
      pb[kb][e] = (short)f32_to_bf16(pe);
    }
  rs += __shfl_xor(rs, 16);
  rs += __shfl_xor(rs, 32);
  l_run += rs;

  // .d drain V(t) DMA only (12 prefetch loads stay in flight), .e cross-wave barrier
  if (has_next) asm volatile("s_waitcnt vmcnt(12)" ::: "memory");
  else          asm volatile("s_waitcnt vmcnt(0)" ::: "memory");
  __builtin_amdgcn_s_barrier();
  __builtin_amdgcn_sched_barrier(0);

  // .f stage V(t+1) into the other buffer (drained at next step's .d)
  if (has_next) stageV(Vp, kt + 64, vnext, tid);

  // .g PV: O^T[dh][q] += V^T-frag x P^T-frag (per-D interleave, low VGPR)
  const char* vb = (const char*)vbuf + 8 * lane;
#pragma unroll
  for (int D = 0; D < 4; ++D) {
    bf16x4 va[4];
#pragma unroll
    for (int kb = 0; kb < 4; ++kb) va[kb] = tr_read(vb + 2048 * D + 512 * kb);
    asm volatile("s_waitcnt lgkmcnt(0)" ::: "memory");
    __builtin_amdgcn_sched_barrier(0);
    __builtin_amdgcn_s_setprio(1);
#pragma unroll
    for (int kb = 0; kb < 4; ++kb) oacc[D] = MFMA16(va[kb], pb[kb], oacc[D]);
    __builtin_amdgcn_s_setprio(0);
  }
}

__global__ __launch_bounds__(256) void flash_attn(
    const u16* __restrict__ Qh, const u16* __restrict__ Kh, const u16* __restrict__ Vh,
    const float* __restrict__ mask, u16* __restrict__ Ob)
{
  const int hb = blockIdx.y;
  const int qb = blockIdx.x * 64;
  const u16* Qp = Qh + (size_t)hb * S_LEN * HDIM;
  const u16* Kp = Kh + (size_t)hb * S_LEN * HDIM;
  const u16* Vp = Vh + (size_t)hb * S_LEN * HDIM;
  u16* Op = Ob + (size_t)hb * S_LEN * HDIM;
  const int tid = threadIdx.x;
  const int wave = tid >> 6, lane = tid & 63;
  const int l15 = lane & 15, l4 = lane >> 4;
  const int qrow = qb + wave * 16 + l15;   // this lane's q row

  // Q B-frags (col = q = l15, k = dh), hoisted
  bf16x8 bq0 = *(const bf16x8*)&Qp[(size_t)qrow * HDIM + 8 * l4];
  bf16x8 bq1 = *(const bf16x8*)&Qp[(size_t)qrow * HDIM + 32 + 8 * l4];

  __shared__ u16 Vlds[2][4096];   // two 64key x 64dh subtiled buffers (8KB each)
  stageV(Vp, 0, &Vlds[0][0], tid);

  // prologue: tile-0 K-frags + mask into register set A
  bf16x8 kA0[4], kA1[4], kB0[4], kB1[4];
  float4 mA[4], mB[4];
#pragma unroll
  for (int kb = 0; kb < 4; ++kb) {
    kA0[kb] = *(const bf16x8*)&Kp[(size_t)(16 * kb + l15) * HDIM + 8 * l4];
    kA1[kb] = *(const bf16x8*)&Kp[(size_t)(16 * kb + l15) * HDIM + 32 + 8 * l4];
    mA[kb]  = *(const float4*)&mask[(size_t)qrow * S_LEN + 16 * kb + 4 * l4];
  }

  float m_run = -1e30f, l_run = 0.f;
  f32x4 oacc[4];
#pragma unroll
  for (int D = 0; D < 4; ++D) oacc[D] = (f32x4){0.f, 0.f, 0.f, 0.f};

  for (int kt = 0; kt < S_LEN; kt += 128) {
    fa_step(kt, true, Kp, mask, Vp, qrow, l15, l4, lane, tid, bq0, bq1,
            kA0, kA1, mA, kB0, kB1, mB, &Vlds[0][0], &Vlds[1][0], m_run, l_run, oacc);
    fa_step(kt + 64, kt + 128 < S_LEN, Kp, mask, Vp, qrow, l15, l4, lane, tid, bq0, bq1,
            kB0, kB1, mB, kA0, kA1, mA, &Vlds[1][0], &Vlds[0][0], m_run, l_run, oacc);
  }

  // epilogue: O[q][dh] = O^T / l
  const float inv = 1.0f / l_run;
#pragma unroll
  for (int D = 0; D < 4; ++D) {
    u16x4 ov;
#pragma unroll
    for (int j = 0; j < 4; ++j) ov[j] = f32_to_bf16(oacc[D][j] * inv);
    *(u16x4*)&Op[(size_t)qrow * HDIM + 16 * D + 4 * l4] = ov;
  }
}

// ---------------- launch ----------------
extern "C" void kernel_launch(void* const* d_in, const int* in_sizes, int n_in,
                              void* d_out, int out_size, void* d_ws, size_t ws_size,
                              hipStream_t stream) {
  const float* q    = (const float*)d_in[0];
  const float* k    = (const float*)d_in[1];
  const float* v    = (const float*)d_in[2];
  const float* mask = (const float*)d_in[3];
  const float* Wq   = (const float*)d_in[4];
  const float* bq   = (const float*)d_in[5];
  const float* Wk   = (const float*)d_in[6];
  const float* bk   = (const float*)d_in[7];
  const float* Wv   = (const float*)d_in[8];
  const float* bv   = (const float*)d_in[9];
  const float* Wo   = (const float*)d_in[10];
  const float* bo   = (const float*)d_in[11];
  float* out = (float*)d_out;

  char* ws = (char*)d_ws;
  const size_t TEN = (size_t)MROWS * DM * sizeof(u16);  // 8 MB
  const size_t WSZ = (size_t)DM * DM * sizeof(u16);     // 2 MB
  u16* qb_ = (u16*)(ws);
  u16* kb_ = (u16*)(ws + TEN);
  u16* vb_ = (u16*)(ws + 2 * TEN);
  u16* wqb = (u16*)(ws + 3 * TEN);
  u16* wkb = (u16*)(ws + 3 * TEN + WSZ);
  u16* wvb = (u16*)(ws + 3 * TEN + 2 * WSZ);
  u16* wob = (u16*)(ws + 3 * TEN + 3 * WSZ);
  u16* Qh  = (u16*)(ws + 3 * TEN + 4 * WSZ);
  u16* Kh  = (u16*)(ws + 4 * TEN + 4 * WSZ);
  u16* Vh  = (u16*)(ws + 5 * TEN + 4 * WSZ);
  u16* Ob  = (u16*)(ws + 6 * TEN + 4 * WSZ);

  const int n8_t = MROWS * DM / 8;   // 524288
  const int n8_w = DM * DM / 8;      // 131072
  cast4_f32_bf16<<<dim3(1024, 3), 256, 0, stream>>>(q, qb_, k, kb_, v, vb_, q, qb_, n8_t);
  cast4_f32_bf16<<<dim3(256, 4), 256, 0, stream>>>(Wq, wqb, Wk, wkb, Wv, wvb, Wo, wob, n8_w);

  const dim3 ggrid(DM / 64, MROWS / 128);  // (16, 32) = 512 blocks
  gemm_bt<0><<<ggrid, 256, 0, stream>>>(qb_, wqb, bq, nullptr, Qh, MROWS, DM, DM);
  gemm_bt<0><<<ggrid, 256, 0, stream>>>(kb_, wkb, bk, nullptr, Kh, MROWS, DM, DM);
  gemm_bt<0><<<ggrid, 256, 0, stream>>>(vb_, wvb, bv, nullptr, Vh, MROWS, DM, DM);

  flash_attn<<<dim3(S_LEN / 64, NHEAD * BATCH), 256, 0, stream>>>(Qh, Kh, Vh, mask, Ob);

  gemm_bt<1><<<ggrid, 256, 0, stream>>>(Ob, wob, bo, out, nullptr, MROWS, DM, DM);
}

// Round 4
// 262.179 us; speedup vs baseline: 1.3621x; 1.1868x over previous
//
#include <hip/hip_runtime.h>
#include <hip/hip_bf16.h>
#include <cstdint>
#include <cstddef>

typedef unsigned short u16;
typedef short bf16x8 __attribute__((ext_vector_type(8)));
typedef short bf16x4 __attribute__((ext_vector_type(4)));
typedef unsigned short u16x8 __attribute__((ext_vector_type(8)));
typedef unsigned short u16x4 __attribute__((ext_vector_type(4)));
typedef float f32x4 __attribute__((ext_vector_type(4)));

#define S_LEN 2048
#define BATCH 2
#define DM 1024
#define NHEAD 16
#define HDIM 64
#define MROWS (S_LEN * BATCH)  // 4096
#define LOG2E 1.44269504088896340736f

__device__ __forceinline__ u16 f32_to_bf16(float f) {
  union { float f; uint32_t u; } v; v.f = f;
  uint32_t u = v.u;
  u += 0x7FFFu + ((u >> 16) & 1u);  // RNE
  return (u16)(u >> 16);
}
__device__ __forceinline__ float bf2f(u16 x) {
  union { float f; uint32_t u; } v; v.u = ((uint32_t)x) << 16; return v.f;
}

__device__ __forceinline__ void gload_lds16(const void* g, void* l) {
  __builtin_amdgcn_global_load_lds(
      (const __attribute__((address_space(1))) void*)g,
      (__attribute__((address_space(3))) void*)l, 16, 0, 0);
}

// hardware transpose read: 4 bf16 per lane
__device__ __forceinline__ bf16x4 tr_read(const void* lp) {
  bf16x4 d;
  auto p = (const __attribute__((address_space(3))) short*)lp;
  asm volatile("ds_read_b64_tr_b16 %0, %1" : "=v"(d) : "v"(p));
  return d;
}

#if __has_builtin(__builtin_amdgcn_mfma_f32_16x16x16_bf16)
#define MFMA16(a, b, c) __builtin_amdgcn_mfma_f32_16x16x16_bf16(a, b, c, 0, 0, 0)
#elif __has_builtin(__builtin_amdgcn_mfma_f32_16x16x16bf16_1k)
#define MFMA16(a, b, c) __builtin_amdgcn_mfma_f32_16x16x16bf16_1k(a, b, c, 0, 0, 0)
#else
__device__ __forceinline__ f32x4 mfma16_asm(bf16x4 a, bf16x4 b, f32x4 c) {
  f32x4 d;
  asm volatile("v_mfma_f32_16x16x16_bf16 %0, %1, %2, %3\n\ts_nop 7\n\ts_nop 7"
               : "=&v"(d) : "v"(a), "v"(b), "v"(c));
  return d;
}
#define MFMA16(a, b, c) mfma16_asm(a, b, c)
#endif

// ---------------- fused fp32 -> bf16 casts (4 tensors, per-tensor scale) -------
__global__ void cast4_f32_bf16(const float* __restrict__ s0, u16* __restrict__ d0,
                               const float* __restrict__ s1, u16* __restrict__ d1,
                               const float* __restrict__ s2, u16* __restrict__ d2,
                               const float* __restrict__ s3, u16* __restrict__ d3,
                               float4 scales, int n8) {
  const int which = blockIdx.y;
  const float* src = which == 0 ? s0 : which == 1 ? s1 : which == 2 ? s2 : s3;
  u16* dst = which == 0 ? d0 : which == 1 ? d1 : which == 2 ? d2 : d3;
  const float sc = which == 0 ? scales.x : which == 1 ? scales.y : which == 2 ? scales.z : scales.w;
  int i = blockIdx.x * blockDim.x + threadIdx.x;
  const int stride = gridDim.x * blockDim.x;
  for (; i < n8; i += stride) {
    const float4* s = (const float4*)(src + (size_t)i * 8);
    float4 a = s[0];
    float4 b = s[1];
    u16x8 o;
    o[0] = f32_to_bf16(a.x * sc); o[1] = f32_to_bf16(a.y * sc);
    o[2] = f32_to_bf16(a.z * sc); o[3] = f32_to_bf16(a.w * sc);
    o[4] = f32_to_bf16(b.x * sc); o[5] = f32_to_bf16(b.y * sc);
    o[6] = f32_to_bf16(b.z * sc); o[7] = f32_to_bf16(b.w * sc);
    *(u16x8*)(dst + (size_t)i * 8) = o;
  }
}

// ---------------- bf16 GEMM: C = (A @ B^T + bias) * oscale  (BM=128,BN=64,BK=32)
template <int MODE>
__global__ __launch_bounds__(256) void gemm_bt(
    const u16* __restrict__ A, const u16* __restrict__ Bw, const float* __restrict__ bias,
    float* __restrict__ outF, u16* __restrict__ outP, int M, int N, int K, float oscale)
{
  __shared__ u16 As[128 * 32];
  __shared__ u16 Bs[64 * 32];
  const int tid = threadIdx.x;
  const int wave = tid >> 6, lane = tid & 63;
  const int l15 = lane & 15, l4 = lane >> 4;
  const int wr = wave >> 1, wc = wave & 1;
  const int rowBase = blockIdx.y * 128, colBase = blockIdx.x * 64;

  f32x4 acc[4][2];
#pragma unroll
  for (int m = 0; m < 4; ++m)
#pragma unroll
    for (int n = 0; n < 2; ++n) acc[m][n] = (f32x4){0.f, 0.f, 0.f, 0.f};

  for (int k0 = 0; k0 < K; k0 += 32) {
#pragma unroll
    for (int c = 0; c < 2; ++c) {
      const int ldsbyte = wave * 2048 + c * 1024;
      const int elt = (ldsbyte >> 1) + lane * 8;
      const int r = elt >> 5, cc = elt & 31;
      gload_lds16(A + (size_t)(rowBase + r) * K + k0 + cc, (char*)As + ldsbyte);
    }
    {
      const int ldsbyte = wave * 1024;
      const int elt = (ldsbyte >> 1) + lane * 8;
      const int r = elt >> 5, cc = elt & 31;
      gload_lds16(Bw + (size_t)(colBase + r) * K + k0 + cc, (char*)Bs + ldsbyte);
    }
    __syncthreads();

    bf16x8 af[4], bfr[2];
#pragma unroll
    for (int m = 0; m < 4; ++m)
      af[m] = *(const bf16x8*)&As[(wr * 64 + m * 16 + l15) * 32 + 8 * l4];
#pragma unroll
    for (int n = 0; n < 2; ++n)
      bfr[n] = *(const bf16x8*)&Bs[(wc * 32 + n * 16 + l15) * 32 + 8 * l4];
#pragma unroll
    for (int m = 0; m < 4; ++m)
#pragma unroll
      for (int n = 0; n < 2; ++n)
        acc[m][n] = __builtin_amdgcn_mfma_f32_16x16x32_bf16(af[m], bfr[n], acc[m][n], 0, 0, 0);
    __syncthreads();
  }

#pragma unroll
  for (int m = 0; m < 4; ++m)
#pragma unroll
    for (int n = 0; n < 2; ++n)
#pragma unroll
      for (int j = 0; j < 4; ++j) {
        const int row = rowBase + wr * 64 + m * 16 + 4 * l4 + j;
        const int col = colBase + wc * 32 + n * 16 + l15;
        const float vv = (acc[m][n][j] + bias[col]) * oscale;
        if (MODE == 0) {
          const int s = row >> 1, b = row & 1, h = col >> 6, dh = col & 63;
          outP[((size_t)(h * BATCH + b) * S_LEN + s) * HDIM + dh] = f32_to_bf16(vv);
        } else {
          outF[(size_t)row * N + col] = vv;
        }
      }
}

// ---------------- flash attention v4 (fat waves: 32 q/wave) ----------------
// V LDS layout [dh/16][key/4][key%4][dh%16]; tr_read at base+8*lane gives the
// 16x16x16 A-frag of V^T (row = dh = lane&15, k = key = 4*(lane>>4)+e).
__device__ __forceinline__ void stageV(const u16* __restrict__ Vp, int kt, u16* dst, int tid) {
#pragma unroll
  for (int h = 0; h < 2; ++h) {
    const int c = tid + 256 * h;                     // chunk id, 16B each
    const int key = 4 * ((c >> 3) & 15) + ((c >> 1) & 3);
    const int dh  = 16 * (c >> 7) + 8 * (c & 1);
    gload_lds16(Vp + (size_t)(kt + key) * HDIM + dh, (char*)dst + 16 * c);
  }
}

// One 64-key tile for 2 q-frags. Scores are in log2 domain (Q pre-scaled by
// 0.125*log2e at projection; mask pre-scaled by log2e at cast).
__device__ __forceinline__ void fa_step(
    int kt, bool has_next,
    const u16* __restrict__ Kp, const u16* __restrict__ maskb, const u16* __restrict__ Vp,
    int qrow0, int qrow1, int l15, int l4, int lane, int tid,
    const bf16x8 (&bq)[2][2],
    bf16x8 (&kc0)[4], bf16x8 (&kc1)[4], u16x4 (&mc)[2][4],
    bf16x8 (&kn0)[4], bf16x8 (&kn1)[4], u16x4 (&mn)[2][4],
    const u16* vbuf, u16* vnext,
    float (&m_run)[2], float (&l_run)[2], f32x4 (&oacc)[2][4])
{
  // .a prefetch next tile: 8 K dwordx4 + 8 mask dwordx2 = 16 VMEM in flight
  if (has_next) {
    const int ktn = kt + 64;
#pragma unroll
    for (int kb = 0; kb < 4; ++kb) {
      kn0[kb] = *(const bf16x8*)&Kp[(size_t)(ktn + 16 * kb + l15) * HDIM + 8 * l4];
      kn1[kb] = *(const bf16x8*)&Kp[(size_t)(ktn + 16 * kb + l15) * HDIM + 32 + 8 * l4];
    }
#pragma unroll
    for (int kb = 0; kb < 4; ++kb) {
      mn[0][kb] = *(const u16x4*)&maskb[(size_t)qrow0 * S_LEN + ktn + 16 * kb + 4 * l4];
      mn[1][kb] = *(const u16x4*)&maskb[(size_t)qrow1 * S_LEN + ktn + 16 * kb + 4 * l4];
    }
  }

  // .b QK^T swapped, K-frags shared across both q-frags
  f32x4 st[2][4];
  __builtin_amdgcn_s_setprio(1);
#pragma unroll
  for (int kb = 0; kb < 4; ++kb) {
#pragma unroll
    for (int f = 0; f < 2; ++f) {
      f32x4 z = (f32x4){0.f, 0.f, 0.f, 0.f};
      z = __builtin_amdgcn_mfma_f32_16x16x32_bf16(kc0[kb], bq[f][0], z, 0, 0, 0);
      z = __builtin_amdgcn_mfma_f32_16x16x32_bf16(kc1[kb], bq[f][1], z, 0, 0, 0);
      st[f][kb] = z;
    }
  }
  __builtin_amdgcn_s_setprio(0);

  // .c online softmax in exp2 domain; lane owns q-rows qrow0 (f=0), qrow1 (f=1)
  float p[2][16];
#pragma unroll
  for (int f = 0; f < 2; ++f)
#pragma unroll
    for (int kb = 0; kb < 4; ++kb)
#pragma unroll
      for (int j = 0; j < 4; ++j)
        p[f][4 * kb + j] = st[f][kb][j] + bf2f((u16)mc[f][kb][j]);

  float tm[2];
#pragma unroll
  for (int f = 0; f < 2; ++f) {
    float t0 = fmaxf(fmaxf(p[f][0], p[f][1]), fmaxf(p[f][2], p[f][3]));
    float t1 = fmaxf(fmaxf(p[f][4], p[f][5]), fmaxf(p[f][6], p[f][7]));
    float t2 = fmaxf(fmaxf(p[f][8], p[f][9]), fmaxf(p[f][10], p[f][11]));
    float t3 = fmaxf(fmaxf(p[f][12], p[f][13]), fmaxf(p[f][14], p[f][15]));
    float t = fmaxf(fmaxf(t0, t1), fmaxf(t2, t3));
    t = fmaxf(t, __shfl_xor(t, 16));
    t = fmaxf(t, __shfl_xor(t, 32));
    tm[f] = t;
  }

  const bool ok = (tm[0] - m_run[0] <= 11.0f) && (tm[1] - m_run[1] <= 11.0f);
  if (!__all(ok)) {   // defer-max: rescale only on real growth (T13)
#pragma unroll
    for (int f = 0; f < 2; ++f) {
      const float mn_ = fmaxf(m_run[f], tm[f]);
      const float fac = exp2f(m_run[f] - mn_);
#pragma unroll
      for (int D = 0; D < 4; ++D)
#pragma unroll
        for (int j = 0; j < 4; ++j) oacc[f][D][j] *= fac;
      l_run[f] *= fac;
      m_run[f] = mn_;
    }
  }

  bf16x4 pb[2][4];
#pragma unroll
  for (int f = 0; f < 2; ++f) {
    float rs = 0.f;
#pragma unroll
    for (int kb = 0; kb < 4; ++kb)
#pragma unroll
      for (int e = 0; e < 4; ++e) {
        const float pe = exp2f(p[f][4 * kb + e] - m_run[f]);
        rs += pe;
        pb[f][kb][e] = (short)f32_to_bf16(pe);
      }
    rs += __shfl_xor(rs, 16);
    rs += __shfl_xor(rs, 32);
    l_run[f] += rs;
  }

  // .d drain V(t) DMA only (16 newer prefetch loads stay in flight), .e barrier
  __builtin_amdgcn_sched_barrier(0);
  if (has_next) asm volatile("s_waitcnt vmcnt(16)" ::: "memory");
  else          asm volatile("s_waitcnt vmcnt(0)" ::: "memory");
  __builtin_amdgcn_s_barrier();
  __builtin_amdgcn_sched_barrier(0);

  // .f stage V(t+1)
  if (has_next) stageV(Vp, kt + 64, vnext, tid);

  // .g PV, rolling tr-read stream: one exposed LDS latency, rest covered
  const char* vb = (const char*)vbuf + 8 * lane;
  bf16x4 va0[4], va1[4], va2[4], va3[4];
#pragma unroll
  for (int kb = 0; kb < 4; ++kb) va0[kb] = tr_read(vb + 512 * kb);
#pragma unroll
  for (int kb = 0; kb < 4; ++kb) va1[kb] = tr_read(vb + 2048 + 512 * kb);
  asm volatile("s_waitcnt lgkmcnt(4)" ::: "memory");
  __builtin_amdgcn_sched_barrier(0);
  __builtin_amdgcn_s_setprio(1);
#pragma unroll
  for (int kb = 0; kb < 4; ++kb) {
    oacc[0][0] = MFMA16(va0[kb], pb[0][kb], oacc[0][0]);
    oacc[1][0] = MFMA16(va0[kb], pb[1][kb], oacc[1][0]);
  }
  __builtin_amdgcn_s_setprio(0);
#pragma unroll
  for (int kb = 0; kb < 4; ++kb) va2[kb] = tr_read(vb + 4096 + 512 * kb);
  asm volatile("s_waitcnt lgkmcnt(4)" ::: "memory");
  __builtin_amdgcn_sched_barrier(0);
  __builtin_amdgcn_s_setprio(1);
#pragma unroll
  for (int kb = 0; kb < 4; ++kb) {
    oacc[0][1] = MFMA16(va1[kb], pb[0][kb], oacc[0][1]);
    oacc[1][1] = MFMA16(va1[kb], pb[1][kb], oacc[1][1]);
  }
  __builtin_amdgcn_s_setprio(0);
#pragma unroll
  for (int kb = 0; kb < 4; ++kb) va3[kb] = tr_read(vb + 6144 + 512 * kb);
  asm volatile("s_waitcnt lgkmcnt(4)" ::: "memory");
  __builtin_amdgcn_sched_barrier(0);
  __builtin_amdgcn_s_setprio(1);
#pragma unroll
  for (int kb = 0; kb < 4; ++kb) {
    oacc[0][2] = MFMA16(va2[kb], pb[0][kb], oacc[0][2]);
    oacc[1][2] = MFMA16(va2[kb], pb[1][kb], oacc[1][2]);
  }
  __builtin_amdgcn_s_setprio(0);
  asm volatile("s_waitcnt lgkmcnt(0)" ::: "memory");
  __builtin_amdgcn_sched_barrier(0);
  __builtin_amdgcn_s_setprio(1);
#pragma unroll
  for (int kb = 0; kb < 4; ++kb) {
    oacc[0][3] = MFMA16(va3[kb], pb[0][kb], oacc[0][3]);
    oacc[1][3] = MFMA16(va3[kb], pb[1][kb], oacc[1][3]);
  }
  __builtin_amdgcn_s_setprio(0);
}

__global__ __launch_bounds__(256, 2) void flash_attn(
    const u16* __restrict__ Qh, const u16* __restrict__ Kh, const u16* __restrict__ Vh,
    const u16* __restrict__ maskb, u16* __restrict__ Ob)
{
  const int hb = blockIdx.y;
  const int qb = blockIdx.x * 128;
  const u16* Qp = Qh + (size_t)hb * S_LEN * HDIM;
  const u16* Kp = Kh + (size_t)hb * S_LEN * HDIM;
  const u16* Vp = Vh + (size_t)hb * S_LEN * HDIM;
  u16* Op = Ob + (size_t)hb * S_LEN * HDIM;
  const int tid = threadIdx.x;
  const int wave = tid >> 6, lane = tid & 63;
  const int l15 = lane & 15, l4 = lane >> 4;
  const int qrow0 = qb + wave * 32 + l15;   // frag 0
  const int qrow1 = qrow0 + 16;             // frag 1

  bf16x8 bq[2][2];
  bq[0][0] = *(const bf16x8*)&Qp[(size_t)qrow0 * HDIM + 8 * l4];
  bq[0][1] = *(const bf16x8*)&Qp[(size_t)qrow0 * HDIM + 32 + 8 * l4];
  bq[1][0] = *(const bf16x8*)&Qp[(size_t)qrow1 * HDIM + 8 * l4];
  bq[1][1] = *(const bf16x8*)&Qp[(size_t)qrow1 * HDIM + 32 + 8 * l4];

  __shared__ u16 Vlds[2][4096];   // two 64key x 64dh subtiled buffers (8KB each)
  stageV(Vp, 0, &Vlds[0][0], tid);

  // prologue: tile-0 K-frags + mask into set A
  bf16x8 kA0[4], kA1[4], kB0[4], kB1[4];
  u16x4 mA[2][4], mB[2][4];
#pragma unroll
  for (int kb = 0; kb < 4; ++kb) {
    kA0[kb] = *(const bf16x8*)&Kp[(size_t)(16 * kb + l15) * HDIM + 8 * l4];
    kA1[kb] = *(const bf16x8*)&Kp[(size_t)(16 * kb + l15) * HDIM + 32 + 8 * l4];
    mA[0][kb] = *(const u16x4*)&maskb[(size_t)qrow0 * S_LEN + 16 * kb + 4 * l4];
    mA[1][kb] = *(const u16x4*)&maskb[(size_t)qrow1 * S_LEN + 16 * kb + 4 * l4];
  }

  float m_run[2] = {-1e30f, -1e30f}, l_run[2] = {0.f, 0.f};
  f32x4 oacc[2][4];
#pragma unroll
  for (int f = 0; f < 2; ++f)
#pragma unroll
    for (int D = 0; D < 4; ++D) oacc[f][D] = (f32x4){0.f, 0.f, 0.f, 0.f};

  for (int kt = 0; kt < S_LEN; kt += 128) {
    fa_step(kt, true, Kp, maskb, Vp, qrow0, qrow1, l15, l4, lane, tid, bq,
            kA0, kA1, mA, kB0, kB1, mB, &Vlds[0][0], &Vlds[1][0], m_run, l_run, oacc);
    fa_step(kt + 64, kt + 128 < S_LEN, Kp, maskb, Vp, qrow0, qrow1, l15, l4, lane, tid, bq,
            kB0, kB1, mB, kA0, kA1, mA, &Vlds[1][0], &Vlds[0][0], m_run, l_run, oacc);
  }

  // epilogue
#pragma unroll
  for (int f = 0; f < 2; ++f) {
    const float inv = 1.0f / l_run[f];
    const int qr = f == 0 ? qrow0 : qrow1;
#pragma unroll
    for (int D = 0; D < 4; ++D) {
      u16x4 ov;
#pragma unroll
      for (int j = 0; j < 4; ++j) ov[j] = f32_to_bf16(oacc[f][D][j] * inv);
      *(u16x4*)&Op[(size_t)qr * HDIM + 16 * D + 4 * l4] = ov;
    }
  }
}

// ---------------- launch ----------------
extern "C" void kernel_launch(void* const* d_in, const int* in_sizes, int n_in,
                              void* d_out, int out_size, void* d_ws, size_t ws_size,
                              hipStream_t stream) {
  const float* q    = (const float*)d_in[0];
  const float* k    = (const float*)d_in[1];
  const float* v    = (const float*)d_in[2];
  const float* mask = (const float*)d_in[3];
  const float* Wq   = (const float*)d_in[4];
  const float* bq   = (const float*)d_in[5];
  const float* Wk   = (const float*)d_in[6];
  const float* bk   = (const float*)d_in[7];
  const float* Wv   = (const float*)d_in[8];
  const float* bv   = (const float*)d_in[9];
  const float* Wo   = (const float*)d_in[10];
  const float* bo   = (const float*)d_in[11];
  float* out = (float*)d_out;

  char* ws = (char*)d_ws;
  const size_t TEN = (size_t)MROWS * DM * sizeof(u16);  // 8 MB
  const size_t WSZ = (size_t)DM * DM * sizeof(u16);     // 2 MB
  u16* qb_ = (u16*)(ws);
  u16* kb_ = (u16*)(ws + TEN);
  u16* vb_ = (u16*)(ws + 2 * TEN);
  u16* wqb = (u16*)(ws + 3 * TEN);
  u16* wkb = (u16*)(ws + 3 * TEN + WSZ);
  u16* wvb = (u16*)(ws + 3 * TEN + 2 * WSZ);
  u16* wob = (u16*)(ws + 3 * TEN + 3 * WSZ);
  u16* Qh  = (u16*)(ws + 3 * TEN + 4 * WSZ);
  u16* Kh  = (u16*)(ws + 4 * TEN + 4 * WSZ);
  u16* Vh  = (u16*)(ws + 5 * TEN + 4 * WSZ);
  u16* Ob  = (u16*)(ws + 6 * TEN + 4 * WSZ);
  u16* maskb = (u16*)(ws + 7 * TEN + 4 * WSZ);  // 8 MB (S*S bf16, pre-scaled by log2e)

  const int n8_t = MROWS * DM / 8;   // 524288 (== S*S/8 for the mask)
  const int n8_w = DM * DM / 8;      // 131072
  cast4_f32_bf16<<<dim3(1024, 4), 256, 0, stream>>>(
      q, qb_, k, kb_, v, vb_, mask, maskb,
      make_float4(1.f, 1.f, 1.f, LOG2E), n8_t);
  cast4_f32_bf16<<<dim3(256, 4), 256, 0, stream>>>(
      Wq, wqb, Wk, wkb, Wv, wvb, Wo, wob,
      make_float4(1.f, 1.f, 1.f, 1.f), n8_w);

  const dim3 ggrid(DM / 64, MROWS / 128);  // (16, 32) = 512 blocks
  const float qscale = 0.125f * LOG2E;     // fold 1/sqrt(hd) and log2e into Q
  gemm_bt<0><<<ggrid, 256, 0, stream>>>(qb_, wqb, bq, nullptr, Qh, MROWS, DM, DM, qscale);
  gemm_bt<0><<<ggrid, 256, 0, stream>>>(kb_, wkb, bk, nullptr, Kh, MROWS, DM, DM, 1.f);
  gemm_bt<0><<<ggrid, 256, 0, stream>>>(vb_, wvb, bv, nullptr, Vh, MROWS, DM, DM, 1.f);

  flash_attn<<<dim3(S_LEN / 128, NHEAD * BATCH), 256, 0, stream>>>(Qh, Kh, Vh, maskb, Ob);

  gemm_bt<1><<<ggrid, 256, 0, stream>>>(Ob, wob, bo, out, nullptr, MROWS, DM, DM, 1.f);
}